// Round 7
// baseline (162.414 us; speedup 1.0000x reference)
//
#include <hip/hip_runtime.h>
#include <stdint.h>

#define B_ 128
#define Q_ 2048
#define C_ 8
#define L_ 256
#define K_ 64
#define S_ 1985            // Q - K + 1
#define KC_ 512            // K*C
#define BMR_ 256           // windows per block tile (rows)
#define BNC_ 64            // shapelet cols per block tile
#define NMT_ 8             // 2048 / 256 m-tiles
#define NNT_ 4             // 256 / 64 n-tiles

typedef short s16x8 __attribute__((ext_vector_type(8)));
typedef float f32x16 __attribute__((ext_vector_type(16)));

__device__ __forceinline__ unsigned short f2bf(float f) {
    unsigned u = __float_as_uint(f);
    u += 0x7FFFu + ((u >> 16) & 1u);        // round-to-nearest-even
    return (unsigned short)(u >> 16);
}
// monotone float -> unsigned encoding (order-preserving), for atomicMin
__device__ __forceinline__ unsigned fenc(float f) {
    unsigned u = __float_as_uint(f);
    return (u & 0x80000000u) ? ~u : (u | 0x80000000u);
}
__device__ __forceinline__ float fdec(unsigned k) {
    unsigned u = (k & 0x80000000u) ? (k ^ 0x80000000u) : ~k;
    return __uint_as_float(u);
}
__device__ __forceinline__ void async_copy16(void* lds_dst, const void* g_src) {
    __builtin_amdgcn_global_load_lds(
        (const __attribute__((address_space(1))) void*)g_src,
        (__attribute__((address_space(3))) void*)lds_dst, 16, 0, 0);
}

// ---- prep: cast ts f32 -> bf16 (contiguous [B][Q][C]) ----
__global__ __launch_bounds__(256) void k_cast_ts(const float* __restrict__ ts,
                                                 uint4* __restrict__ out) {
    int i = blockIdx.x * 256 + threadIdx.x;          // 262144 total, exact
    const float4* p = (const float4*)ts + (size_t)i * 2;
    float4 x = p[0], y = p[1];
    union { unsigned short h[8]; uint4 v; } u;
    u.h[0] = f2bf(x.x); u.h[1] = f2bf(x.y); u.h[2] = f2bf(x.z); u.h[3] = f2bf(x.w);
    u.h[4] = f2bf(y.x); u.h[5] = f2bf(y.y); u.h[6] = f2bf(y.z); u.h[7] = f2bf(y.w);
    out[i] = u.v;
}

// ---- prep: zero the A-overrun pad after tsb (512 rows = 8 KB) ----
__global__ __launch_bounds__(256) void k_pad(uint4* __restrict__ tsb) {
    uint4 z; z.x = z.y = z.z = z.w = 0u;
    tsb[B_ * Q_ + blockIdx.x * 256 + threadIdx.x] = z;
}

// ---- prep: shapelets f32 -> bf16 [L][512] + sh_sq (f32) ----
__global__ __launch_bounds__(64) void k_prep_sh(const float* __restrict__ sh,
                                                uint4* __restrict__ shb,
                                                float* __restrict__ shsq) {
    const int l = blockIdx.x;
    const int t = threadIdx.x;                        // 64
    const float4* p = (const float4*)(sh + (size_t)l * KC_) + t * 2;
    float4 x = p[0], y = p[1];
    union { unsigned short h[8]; uint4 v; } u;
    u.h[0] = f2bf(x.x); u.h[1] = f2bf(x.y); u.h[2] = f2bf(x.z); u.h[3] = f2bf(x.w);
    u.h[4] = f2bf(y.x); u.h[5] = f2bf(y.y); u.h[6] = f2bf(y.z); u.h[7] = f2bf(y.w);
    shb[l * 64 + t] = u.v;
    float ss = x.x*x.x + x.y*x.y + x.z*x.z + x.w*x.w
             + y.x*y.x + y.y*y.y + y.z*y.z + y.w*y.w;
    #pragma unroll
    for (int off = 32; off >= 1; off >>= 1) ss += __shfl_down(ss, off, 64);
    if (t == 0) shsq[l] = ss;
}

// ---- init running-min buffer to "+inf" key ----
__global__ __launch_bounds__(256) void k_init(unsigned* __restrict__ hmin) {
    hmin[blockIdx.x * 256 + threadIdx.x] = 0xFFFFFFFFu;
}

// ---- main: implicit-GEMM conv + fused min-pool, 4 blocks/CU ----
// block: 256 thr = 4 waves as 4m x 1n over 256 rows x 64 cols, acc 2x2.
// A (all K) in LDS (5 KB). B chunked: 4 phases x 128k, dbuf 2x16 KB.
// LDS ~38 KB -> 4 blocks/CU = 4 waves/SIMD (the point of this round).
// B swizzle within a col's 16-slot chunk region: slot' = slot ^ (col&15)
// (2-way quad aliasing only, which is free); same involution on source.
__global__ __launch_bounds__(256, 4) void k_main(
    const float* __restrict__ ts,         // f32 [B][Q][C]
    const uint4* __restrict__ tsb,        // bf16 [B][Q][C] (+512 zero pad rows)
    const char*  __restrict__ shb,        // bf16 [L][512] bytes
    const float* __restrict__ shsq,       // [L]
    unsigned*    __restrict__ hmin)       // [B][L] encoded min
{
    __shared__ uint4 b_lds4[2][1024];     // 2 x (64 cols x 16 slots x 16B) = 32 KB
    __shared__ uint4 a_lds4[320];         // 320 ts-rows x 8ch bf16 = 5 KB
    __shared__ float rsq[320];            // per-row sq; rows 0..255 become wq

    const int mt   = blockIdx.x >> 2;     // 0..7
    const int nt   = blockIdx.x & 3;      // 0..3
    const int b    = blockIdx.y;
    const int s0   = mt * BMR_;
    const int c0   = nt * BNC_;
    const int tid  = threadIdx.x;
    const int lane = tid & 63;
    const int wv   = tid >> 6;            // 0..3 = row group of 64
    const int l31  = lane & 31;
    const int hi   = lane >> 5;

    const int scol = (wv * 4) * 4;        // staging col base helper (see below)
    // stage one 128k B-chunk (16 KB) into buf: 4 async copies/thread.
    // flat byte f = (wv*4+it)*1024 + lane*16; col = f>>8, slot j = lane&15.
    #define STAGE_B(bufp, p)                                                   \
        {                                                                      \
            _Pragma("unroll")                                                  \
            for (int it = 0; it < 4; ++it) {                                   \
                int col = (wv * 4 + it) * 4 + (lane >> 4);                     \
                int j   = lane & 15;                                           \
                const char* g = shb + (size_t)(c0 + col) * 1024 + (p) * 256    \
                              + ((j ^ (col & 15)) << 4);                       \
                async_copy16((char*)&b_lds4[bufp][(wv * 4 + it) * 64]          \
                             + lane * 16, g);                                  \
            }                                                                  \
        }

    STAGE_B(0, 0)
    // stage A (all K): 320 rows x 16B via async copies (linear, coalesced)
    {
        const char* gA = (const char*)(tsb + (size_t)b * Q_ + s0);
        async_copy16((char*)a_lds4 + (wv * 64) * 16 + lane * 16,
                     gA + tid * 16);
        if (tid < 64)                      // wave 0 only, full wave
            async_copy16((char*)a_lds4 + 256 * 16 + lane * 16,
                         gA + (256 + tid) * 16);
    }
    // per-row sum of squares (f32, exact path)
    for (int rr = tid; rr < 320; rr += 256) {
        int row = s0 + rr;
        float r = 0.f;
        if (row < Q_) {
            const float4* pf = (const float4*)(ts + ((size_t)b * Q_ + row) * C_);
            float4 x = pf[0], y = pf[1];
            r = x.x*x.x + x.y*x.y + x.z*x.z + x.w*x.w
              + y.x*y.x + y.y*y.y + y.z*y.z + y.w*y.w;
        }
        rsq[rr] = r;
    }
    __syncthreads();   // B0 + A landed, rsq ready

    // window sq-norm into register, then overwrite rsq[tid] (wq reuse)
    float wsum = 0.f;
    #pragma unroll 16
    for (int k = 0; k < K_; ++k) wsum += rsq[tid + k];
    __syncthreads();   // all reads of raw rsq done
    rsq[tid] = (s0 + tid < S_) ? wsum : __builtin_inff();

    const f32x16 fz = {0.f,0.f,0.f,0.f,0.f,0.f,0.f,0.f,
                       0.f,0.f,0.f,0.f,0.f,0.f,0.f,0.f};
    f32x16 acc00 = fz, acc01 = fz;        // row-frag 0, col-frags 0/1
    f32x16 acc10 = fz, acc11 = fz;        // row-frag 1 (+32 rows)

    const char* ab    = (const char*)a_lds4;
    const int   abase = (wv * 64 + l31 + hi) * 16;   // ts-row byte base
    const int   bswz  = l31 & 15;
    const int   bcol  = l31 * 256;                   // byte base of B col

    #define PHASE(p, bufp)                                                     \
        {                                                                      \
            const char* bb = (const char*)&b_lds4[bufp][0];                    \
            _Pragma("unroll")                                                  \
            for (int kkl = 0; kkl < 8; ++kkl) {                                \
                int kk = (p) * 8 + kkl;                                        \
                s16x8 a0 = *(const s16x8*)(ab + abase + kk * 32);              \
                s16x8 a1 = *(const s16x8*)(ab + abase + kk * 32 + 512);        \
                int slot = ((2 * kkl + hi) ^ bswz) << 4;                       \
                s16x8 b0v = *(const s16x8*)(bb + bcol + slot);                 \
                s16x8 b1v = *(const s16x8*)(bb + bcol + slot + 8192);          \
                __builtin_amdgcn_s_setprio(1);                                 \
                acc00 = __builtin_amdgcn_mfma_f32_32x32x16_bf16(a0, b0v, acc00, 0, 0, 0); \
                acc01 = __builtin_amdgcn_mfma_f32_32x32x16_bf16(a0, b1v, acc01, 0, 0, 0); \
                acc10 = __builtin_amdgcn_mfma_f32_32x32x16_bf16(a1, b0v, acc10, 0, 0, 0); \
                acc11 = __builtin_amdgcn_mfma_f32_32x32x16_bf16(a1, b1v, acc11, 0, 0, 0); \
                __builtin_amdgcn_s_setprio(0);                                 \
            }                                                                  \
        }

    STAGE_B(1, 1)
    PHASE(0, 0)
    __syncthreads();
    STAGE_B(0, 2)
    PHASE(1, 1)
    __syncthreads();
    STAGE_B(1, 3)
    PHASE(2, 0)
    __syncthreads();
    PHASE(3, 1)
    // no barrier needed: epilogue reads only rsq (written pre-phase0,
    // barriers since) and registers.

    // epilogue: dist = (wq - 2*cross + shsq)/512, min over this wave's rows
    const float inf = __builtin_inff();
    float m0 = inf, m1 = inf;
    {
        int rb = wv * 64 + 4 * hi;
        #pragma unroll
        for (int r = 0; r < 16; ++r) {
            int row = rb + (r & 3) + 8 * (r >> 2);
            float w0 = rsq[row];          // +inf masks invalid windows
            float w1 = rsq[row + 32];
            m0 = fminf(m0, fminf(w0 - 2.f * acc00[r], w1 - 2.f * acc10[r]));
            m1 = fminf(m1, fminf(w0 - 2.f * acc01[r], w1 - 2.f * acc11[r]));
        }
    }
    const int colg = c0 + l31;
    m0 = (m0 + shsq[colg])      * (1.f / 512.f);
    m1 = (m1 + shsq[colg + 32]) * (1.f / 512.f);
    m0 = fminf(m0, __shfl_xor(m0, 32, 64));
    m1 = fminf(m1, __shfl_xor(m1, 32, 64));
    if (hi == 0) {
        atomicMin(&hmin[b * L_ + colg],      fenc(m0));
        atomicMin(&hmin[b * L_ + colg + 32], fenc(m1));
    }
    (void)scol;
}

// ---- final: gating + FC [B,L] -> [B,2] ----
__global__ __launch_bounds__(256) void k_final(const unsigned* __restrict__ hmin,
                                               const float* __restrict__ gating,
                                               const float* __restrict__ w,
                                               const float* __restrict__ bias,
                                               float* __restrict__ out) {
    const int b = blockIdx.x, t = threadIdx.x;       // 256 threads = L
    float v = fdec(hmin[b * L_ + t]);
    float g = 1.f / (1.f + __expf(-gating[t]));
    float mg = v * g;
    float p0 = mg * w[t];
    float p1 = mg * w[L_ + t];
    #pragma unroll
    for (int off = 32; off >= 1; off >>= 1) {
        p0 += __shfl_down(p0, off, 64);
        p1 += __shfl_down(p1, off, 64);
    }
    __shared__ float r0[4], r1[4];
    int wvi = t >> 6, ln = t & 63;
    if (ln == 0) { r0[wvi] = p0; r1[wvi] = p1; }
    __syncthreads();
    if (t == 0) {
        out[b * 2 + 0] = r0[0] + r0[1] + r0[2] + r0[3] + bias[0];
        out[b * 2 + 1] = r1[0] + r1[1] + r1[2] + r1[3] + bias[1];
    }
}

extern "C" void kernel_launch(void* const* d_in, const int* in_sizes, int n_in,
                              void* d_out, int out_size, void* d_ws, size_t ws_size,
                              hipStream_t stream) {
    const float* ts     = (const float*)d_in[0];
    const float* sh     = (const float*)d_in[1];
    const float* gating = (const float*)d_in[2];
    const float* fw     = (const float*)d_in[3];
    const float* fb     = (const float*)d_in[4];
    float* out = (float*)d_out;

    char* ws = (char*)d_ws;
    uint4*    tsb  = (uint4*)ws;                               // 4 MiB + 8 KB pad
    char*     shb  = ws + 4202496;                             // 256 KiB
    float*    shsq = (float*)(ws + 4202496 + 262144);          // 1 KiB
    unsigned* hmin = (unsigned*)(ws + 4202496 + 262144 + 1024);// 128 KiB

    k_cast_ts<<<1024, 256, 0, stream>>>(ts, tsb);
    k_pad<<<2, 256, 0, stream>>>(tsb);
    k_prep_sh<<<256, 64, 0, stream>>>(sh, (uint4*)shb, shsq);
    k_init<<<128, 256, 0, stream>>>(hmin);
    dim3 grid(NMT_ * NNT_, B_);
    k_main<<<grid, 256, 0, stream>>>(ts, tsb, shb, shsq, hmin);
    k_final<<<128, 256, 0, stream>>>(hmin, gating, fw, fb, out);
}

// Round 8
// 72.404 us; speedup vs baseline: 2.2432x; 2.2432x over previous
//
#include <hip/hip_runtime.h>
#include <stdint.h>

#define B_ 128
#define Q_ 2048
#define C_ 8
#define L_ 256
#define K_ 64
#define S_ 1985            // Q - K + 1
#define KC_ 512            // K*C
#define BNC_ 64            // shapelet cols per block tile
#define NNT_ 4             // 256 / 64 n-tiles

typedef short s16x8 __attribute__((ext_vector_type(8)));
typedef float f32x16 __attribute__((ext_vector_type(16)));

__device__ __forceinline__ unsigned short f2bf(float f) {
    unsigned u = __float_as_uint(f);
    u += 0x7FFFu + ((u >> 16) & 1u);        // round-to-nearest-even
    return (unsigned short)(u >> 16);
}
// monotone float -> unsigned encoding (order-preserving), for atomicMin
__device__ __forceinline__ unsigned fenc(float f) {
    unsigned u = __float_as_uint(f);
    return (u & 0x80000000u) ? ~u : (u | 0x80000000u);
}
__device__ __forceinline__ float fdec(unsigned k) {
    unsigned u = (k & 0x80000000u) ? (k ^ 0x80000000u) : ~k;
    return __uint_as_float(u);
}
__device__ __forceinline__ void async_copy16(void* lds_dst, const void* g_src) {
    __builtin_amdgcn_global_load_lds(
        (const __attribute__((address_space(1))) void*)g_src,
        (__attribute__((address_space(3))) void*)lds_dst, 16, 0, 0);
}

// ---- prep: cast ts f32 -> bf16 (contiguous [B][Q][C]) ----
__global__ __launch_bounds__(256) void k_cast_ts(const float* __restrict__ ts,
                                                 uint4* __restrict__ out) {
    int i = blockIdx.x * 256 + threadIdx.x;          // 262144 total, exact
    const float4* p = (const float4*)ts + (size_t)i * 2;
    float4 x = p[0], y = p[1];
    union { unsigned short h[8]; uint4 v; } u;
    u.h[0] = f2bf(x.x); u.h[1] = f2bf(x.y); u.h[2] = f2bf(x.z); u.h[3] = f2bf(x.w);
    u.h[4] = f2bf(y.x); u.h[5] = f2bf(y.y); u.h[6] = f2bf(y.z); u.h[7] = f2bf(y.w);
    out[i] = u.v;
}

// ---- prep: zero the A-overrun pad after tsb (512 rows = 8 KB) ----
__global__ __launch_bounds__(256) void k_pad(uint4* __restrict__ tsb) {
    uint4 z; z.x = z.y = z.z = z.w = 0u;
    tsb[B_ * Q_ + blockIdx.x * 256 + threadIdx.x] = z;
}

// ---- prep: shapelets f32 -> bf16 [L][512] + sh_sq (f32) ----
__global__ __launch_bounds__(64) void k_prep_sh(const float* __restrict__ sh,
                                                uint4* __restrict__ shb,
                                                float* __restrict__ shsq) {
    const int l = blockIdx.x;
    const int t = threadIdx.x;                        // 64
    const float4* p = (const float4*)(sh + (size_t)l * KC_) + t * 2;
    float4 x = p[0], y = p[1];
    union { unsigned short h[8]; uint4 v; } u;
    u.h[0] = f2bf(x.x); u.h[1] = f2bf(x.y); u.h[2] = f2bf(x.z); u.h[3] = f2bf(x.w);
    u.h[4] = f2bf(y.x); u.h[5] = f2bf(y.y); u.h[6] = f2bf(y.z); u.h[7] = f2bf(y.w);
    shb[l * 64 + t] = u.v;
    float ss = x.x*x.x + x.y*x.y + x.z*x.z + x.w*x.w
             + y.x*y.x + y.y*y.y + y.z*y.z + y.w*y.w;
    #pragma unroll
    for (int off = 32; off >= 1; off >>= 1) ss += __shfl_down(ss, off, 64);
    if (t == 0) shsq[l] = ss;
}

// ---- prep: window sq-norms wqg[B][2048] (+inf for invalid windows) ----
__global__ __launch_bounds__(256) void k_wq(const float* __restrict__ ts,
                                            float* __restrict__ wqg) {
    const int b = blockIdx.x;                         // 128 blocks
    const int t = threadIdx.x;                        // 256
    __shared__ float t2[2048];
    // per-row sq-sum, coalesced by row-interleave
    #pragma unroll
    for (int j = 0; j < 8; ++j) {
        int r = j * 256 + t;
        const float4* p = (const float4*)(ts + ((size_t)b * Q_ + r) * C_);
        float4 x = p[0], y = p[1];
        t2[r] = x.x*x.x + x.y*x.y + x.z*x.z + x.w*x.w
              + y.x*y.x + y.y*y.y + y.z*y.z + y.w*y.w;
    }
    __syncthreads();
    const float inf = __builtin_inff();
    int s0 = t * 8;
    float w = 0.f;
    if (s0 < S_) {
        #pragma unroll 16
        for (int k = 0; k < K_; ++k) w += t2[s0 + k];
    }
    #pragma unroll
    for (int j = 0; j < 8; ++j) {
        int s = s0 + j;
        wqg[(size_t)b * Q_ + s] = (s < S_) ? w : inf;
        if (s + 1 < S_) w = w + t2[s + K_] - t2[s];   // slide window
    }
}

// ---- init running-min buffer to "+inf" key ----
__global__ __launch_bounds__(256) void k_init(unsigned* __restrict__ hmin) {
    hmin[blockIdx.x * 256 + threadIdx.x] = 0xFFFFFFFFu;
}

// ---- main: implicit-GEMM conv + fused min-pool, long-lived blocks ----
// grid 4 n-tiles x 128 b = 512 blocks (2/CU). Block stages B (64 cols x
// full K = 64 KB) ONCE, then loops 8 m-tiles, double-buffering the tiny
// A-tile (5 KB) + wq-tile (1 KB) via global_load_lds issued at iter start
// (drain hides under the K-loop). Min-pool accumulates in registers across
// m-iters; single atomic pair per wave at block end.
__global__ __launch_bounds__(256, 2) void k_main(
    const uint4* __restrict__ tsb,        // bf16 [B][Q][C] (+512 zero pad rows)
    const char*  __restrict__ shb,        // bf16 [L][512] bytes
    const float* __restrict__ wqg,        // [B][2048] window norms (+inf tail)
    const float* __restrict__ shsq,       // [L]
    unsigned*    __restrict__ hmin)       // [B][L] encoded min
{
    __shared__ uint4 b_lds4[4096];        // 64 cols x 64 chunks x 16B = 64 KB
    __shared__ uint4 a_lds4[2][320];      // dbuf A: 2 x 5 KB
    __shared__ float wqt[2][256];         // dbuf wq tile: 2 x 1 KB

    const int nt   = blockIdx.x;          // 0..3
    const int b    = blockIdx.y;
    const int c0   = nt * BNC_;
    const int tid  = threadIdx.x;
    const int lane = tid & 63;
    const int wv   = tid >> 6;            // 0..3 = row group of 64
    const int l31  = lane & 31;
    const int hi   = lane >> 5;

    // stage A+wq tile for m-tile mi_ into dbuf slot p (async, linear dest)
    #define STAGE_A(p, mi_)                                                    \
        {                                                                      \
            const char* gA = (const char*)(tsb + (size_t)b * Q_ + (mi_) * 256);\
            async_copy16((char*)&a_lds4[p][wv * 64] + lane * 16,               \
                         gA + (wv * 64 + lane) * 16);                          \
            if (wv == 0)                                                       \
                async_copy16((char*)&a_lds4[p][256] + lane * 16,               \
                             gA + (256 + lane) * 16);                          \
            else if (wv == 1)                                                  \
                async_copy16((char*)&wqt[p][0] + lane * 16,                    \
                             (const char*)(wqg + (size_t)b * Q_ + (mi_) * 256) \
                             + lane * 16);                                     \
        }

    // stage B once: 64 cols x 1 KB, one col per wave-issue, 16 cols/wave.
    // swizzle: stored chunk = chunk ^ (col&31); same involution on source.
    #pragma unroll
    for (int it = 0; it < 16; ++it) {
        int col  = wv * 16 + it;
        const char* g = shb + ((size_t)(c0 + col)) * 1024
                      + ((lane ^ (col & 31)) << 4);
        async_copy16((char*)b_lds4 + col * 1024, g);
    }
    STAGE_A(0, 0)
    __syncthreads();   // B + A0 + wq0 landed

    const f32x16 fz = {0.f,0.f,0.f,0.f,0.f,0.f,0.f,0.f,
                       0.f,0.f,0.f,0.f,0.f,0.f,0.f,0.f};
    const float inf = __builtin_inff();
    float rm0 = inf, rm1 = inf;           // running min across m-iters

    const char* bb    = (const char*)b_lds4;
    const int   abase = (wv * 64 + l31 + hi) * 16;   // ts-row byte base
    const int   bcol  = l31 * 1024;                  // B col byte base

    #pragma unroll 1
    for (int mi = 0; mi < 8; ++mi) {
        const int p = mi & 1;
        if (mi < 7) STAGE_A(p ^ 1, mi + 1)           // prefetch next tiles

        f32x16 acc00 = fz, acc01 = fz;    // rows (wv*64..), cols l31 / l31+32
        f32x16 acc10 = fz, acc11 = fz;    // rows +32
        const char* ab = (const char*)&a_lds4[p][0];
        #pragma unroll
        for (int kk = 0; kk < 32; ++kk) {
            s16x8 a0 = *(const s16x8*)(ab + abase + kk * 32);
            s16x8 a1 = *(const s16x8*)(ab + abase + kk * 32 + 512);
            int ch = (((kk << 1) + hi) ^ l31) << 4;
            s16x8 b0 = *(const s16x8*)(bb + bcol + ch);
            s16x8 b1 = *(const s16x8*)(bb + bcol + ch + 32768);  // +32 cols
            __builtin_amdgcn_s_setprio(1);
            acc00 = __builtin_amdgcn_mfma_f32_32x32x16_bf16(a0, b0, acc00, 0, 0, 0);
            acc01 = __builtin_amdgcn_mfma_f32_32x32x16_bf16(a0, b1, acc01, 0, 0, 0);
            acc10 = __builtin_amdgcn_mfma_f32_32x32x16_bf16(a1, b0, acc10, 0, 0, 0);
            acc11 = __builtin_amdgcn_mfma_f32_32x32x16_bf16(a1, b1, acc11, 0, 0, 0);
            __builtin_amdgcn_s_setprio(0);
        }

        // fold this m-tile into running min (wq has +inf at invalid windows)
        {
            int rb = wv * 64 + 4 * hi;
            #pragma unroll
            for (int r = 0; r < 16; ++r) {
                int row = rb + (r & 3) + 8 * (r >> 2);
                float w0 = wqt[p][row];
                float w1 = wqt[p][row + 32];
                rm0 = fminf(rm0, fminf(w0 - 2.f * acc00[r], w1 - 2.f * acc10[r]));
                rm1 = fminf(rm1, fminf(w0 - 2.f * acc01[r], w1 - 2.f * acc11[r]));
            }
        }
        __syncthreads();   // next-iter A/wq staged (issued pre-K-loop) + bufs free
    }

    // block-end epilogue: + shsq (commutes with min), scale, reduce, atomic
    const int colg = c0 + l31;
    rm0 = (rm0 + shsq[colg])      * (1.f / 512.f);
    rm1 = (rm1 + shsq[colg + 32]) * (1.f / 512.f);
    rm0 = fminf(rm0, __shfl_xor(rm0, 32, 64));
    rm1 = fminf(rm1, __shfl_xor(rm1, 32, 64));
    if (hi == 0) {
        atomicMin(&hmin[b * L_ + colg],      fenc(rm0));
        atomicMin(&hmin[b * L_ + colg + 32], fenc(rm1));
    }
}

// ---- final: gating + FC [B,L] -> [B,2] ----
__global__ __launch_bounds__(256) void k_final(const unsigned* __restrict__ hmin,
                                               const float* __restrict__ gating,
                                               const float* __restrict__ w,
                                               const float* __restrict__ bias,
                                               float* __restrict__ out) {
    const int b = blockIdx.x, t = threadIdx.x;       // 256 threads = L
    float v = fdec(hmin[b * L_ + t]);
    float g = 1.f / (1.f + __expf(-gating[t]));
    float mg = v * g;
    float p0 = mg * w[t];
    float p1 = mg * w[L_ + t];
    #pragma unroll
    for (int off = 32; off >= 1; off >>= 1) {
        p0 += __shfl_down(p0, off, 64);
        p1 += __shfl_down(p1, off, 64);
    }
    __shared__ float r0[4], r1[4];
    int wvi = t >> 6, ln = t & 63;
    if (ln == 0) { r0[wvi] = p0; r1[wvi] = p1; }
    __syncthreads();
    if (t == 0) {
        out[b * 2 + 0] = r0[0] + r0[1] + r0[2] + r0[3] + bias[0];
        out[b * 2 + 1] = r1[0] + r1[1] + r1[2] + r1[3] + bias[1];
    }
}

extern "C" void kernel_launch(void* const* d_in, const int* in_sizes, int n_in,
                              void* d_out, int out_size, void* d_ws, size_t ws_size,
                              hipStream_t stream) {
    const float* ts     = (const float*)d_in[0];
    const float* sh     = (const float*)d_in[1];
    const float* gating = (const float*)d_in[2];
    const float* fw     = (const float*)d_in[3];
    const float* fb     = (const float*)d_in[4];
    float* out = (float*)d_out;

    char* ws = (char*)d_ws;
    uint4*    tsb  = (uint4*)ws;                         // 4 MiB + 8 KB pad
    char*     shb  = ws + 4202496;                       // 256 KiB
    float*    shsq = (float*)(ws + 4464640);             // 1 KiB
    unsigned* hmin = (unsigned*)(ws + 4465664);          // 128 KiB
    float*    wqg  = (float*)(ws + 4596736);             // 1 MiB

    k_cast_ts<<<1024, 256, 0, stream>>>(ts, tsb);
    k_pad<<<2, 256, 0, stream>>>(tsb);
    k_prep_sh<<<256, 64, 0, stream>>>(sh, (uint4*)shb, shsq);
    k_wq<<<128, 256, 0, stream>>>(ts, wqg);
    k_init<<<128, 256, 0, stream>>>(hmin);
    dim3 grid(NNT_, B_);
    k_main<<<grid, 256, 0, stream>>>(tsb, shb, wqg, shsq, hmin);
    k_final<<<128, 256, 0, stream>>>(hmin, gating, fw, fb, out);
}

// Round 9
// 66.742 us; speedup vs baseline: 2.4334x; 1.0848x over previous
//
#include <hip/hip_runtime.h>
#include <stdint.h>

#define B_ 128
#define Q_ 2048
#define C_ 8
#define L_ 256
#define K_ 64
#define S_ 1985            // Q - K + 1
#define KC_ 512            // K*C
#define BNC_ 64            // shapelet cols per block tile
#define NNT_ 4             // 256 / 64 n-tiles

typedef short s16x8 __attribute__((ext_vector_type(8)));
typedef float f32x16 __attribute__((ext_vector_type(16)));

__device__ __forceinline__ unsigned short f2bf(float f) {
    unsigned u = __float_as_uint(f);
    u += 0x7FFFu + ((u >> 16) & 1u);        // round-to-nearest-even
    return (unsigned short)(u >> 16);
}
// monotone float -> unsigned encoding (order-preserving), for atomicMin
__device__ __forceinline__ unsigned fenc(float f) {
    unsigned u = __float_as_uint(f);
    return (u & 0x80000000u) ? ~u : (u | 0x80000000u);
}
__device__ __forceinline__ float fdec(unsigned k) {
    unsigned u = (k & 0x80000000u) ? (k ^ 0x80000000u) : ~k;
    return __uint_as_float(u);
}
__device__ __forceinline__ void async_copy16(void* lds_dst, const void* g_src) {
    __builtin_amdgcn_global_load_lds(
        (const __attribute__((address_space(1))) void*)g_src,
        (__attribute__((address_space(3))) void*)lds_dst, 16, 0, 0);
}

// ---- prep: cast ts -> bf16 AND window-norm ext pairs, one ts read ----
// extg[b][s] packs 2 bf16: (-wq/2) split as (hi, residual-lo); invalid
// windows get (-inf, 0) -> GEMM acc = -inf -> dist = +inf (free masking).
__global__ __launch_bounds__(256) void k_prep_ts(const float* __restrict__ ts,
                                                 uint4* __restrict__ tsb,
                                                 unsigned* __restrict__ extg) {
    const int b = blockIdx.x;                         // 128 blocks
    const int t = threadIdx.x;                        // 256
    __shared__ float t2[2048];
    #pragma unroll
    for (int j = 0; j < 8; ++j) {
        int r = j * 256 + t;
        const float4* p = (const float4*)(ts + ((size_t)b * Q_ + r) * C_);
        float4 x = p[0], y = p[1];
        union { unsigned short h[8]; uint4 v; } u;
        u.h[0] = f2bf(x.x); u.h[1] = f2bf(x.y); u.h[2] = f2bf(x.z); u.h[3] = f2bf(x.w);
        u.h[4] = f2bf(y.x); u.h[5] = f2bf(y.y); u.h[6] = f2bf(y.z); u.h[7] = f2bf(y.w);
        tsb[(size_t)b * Q_ + r] = u.v;
        t2[r] = x.x*x.x + x.y*x.y + x.z*x.z + x.w*x.w
              + y.x*y.x + y.y*y.y + y.z*y.z + y.w*y.w;
    }
    __syncthreads();
    int s0 = t * 8;
    float w = 0.f;
    if (s0 < S_) {
        #pragma unroll 16
        for (int k = 0; k < K_; ++k) w += t2[s0 + k];
    }
    #pragma unroll
    for (int j = 0; j < 8; ++j) {
        int s = s0 + j;
        unsigned word = 0x0000FF80u;                  // slot0 = -inf, slot1 = 0
        if (s < S_) {
            float v = -0.5f * w;
            unsigned short hh = f2bf(v);
            float hf = __uint_as_float((unsigned)hh << 16);
            unsigned short ll = f2bf(v - hf);
            word = (unsigned)hh | ((unsigned)ll << 16);
        }
        extg[(size_t)b * Q_ + s] = word;
        if (s + K_ < Q_) w += t2[s + K_] - t2[s];     // slide window
    }
}

// ---- prep: zero A-overrun pad + init running-min keys ----
__global__ __launch_bounds__(256) void k_misc(uint4* __restrict__ tsb,
                                              unsigned* __restrict__ hmin) {
    const int bid = blockIdx.x, t = threadIdx.x;
    if (bid < 2) {
        uint4 z; z.x = z.y = z.z = z.w = 0u;
        tsb[B_ * Q_ + bid * 256 + t] = z;
    } else {
        hmin[(bid - 2) * 256 + t] = 0xFFFFFFFFu;
    }
}

// ---- prep: shapelets f32 -> bf16 [L][512] + sh_sq (f32) ----
__global__ __launch_bounds__(64) void k_prep_sh(const float* __restrict__ sh,
                                                uint4* __restrict__ shb,
                                                float* __restrict__ shsq) {
    const int l = blockIdx.x;
    const int t = threadIdx.x;                        // 64
    const float4* p = (const float4*)(sh + (size_t)l * KC_) + t * 2;
    float4 x = p[0], y = p[1];
    union { unsigned short h[8]; uint4 v; } u;
    u.h[0] = f2bf(x.x); u.h[1] = f2bf(x.y); u.h[2] = f2bf(x.z); u.h[3] = f2bf(x.w);
    u.h[4] = f2bf(y.x); u.h[5] = f2bf(y.y); u.h[6] = f2bf(y.z); u.h[7] = f2bf(y.w);
    shb[l * 64 + t] = u.v;
    float ss = x.x*x.x + x.y*x.y + x.z*x.z + x.w*x.w
             + y.x*y.x + y.y*y.y + y.z*y.z + y.w*y.w;
    #pragma unroll
    for (int off = 32; off >= 1; off >>= 1) ss += __shfl_down(ss, off, 64);
    if (t == 0) shsq[l] = ss;
}

// ---- main: implicit-GEMM conv + fused min-pool, acc 4x2, wq-in-GEMM ----
// grid 4 n-tiles x 128 b = 512 blocks (2/CU). Block stages B (64 cols x
// full K = 64 KB) ONCE, then 4 m-iters of 512 windows. Wave tile 128x64
// (acc 4x2): 6 ds_read_b128 per 8 MFMAs. wq folds in via a K-extension
// MFMA step (A = -wq/2 bf16 pair from 1 ds_read_b32; B = constant 1s).
__global__ __launch_bounds__(256, 2) void k_main(
    const uint4* __restrict__ tsb,        // bf16 [B][Q][C] (+512 zero pad rows)
    const char*  __restrict__ shb,        // bf16 [L][512] bytes
    const unsigned* __restrict__ extg,    // [B][2048] packed (-wq/2) bf16 pairs
    const float* __restrict__ shsq,       // [L]
    unsigned*    __restrict__ hmin)       // [B][L] encoded min
{
    __shared__ uint4 b_lds4[4096];        // 64 cols x 64 chunks x 16B = 64 KB
    __shared__ uint4 a_lds4[576];         // 576 ts-rows x 16B = 9 KB
    __shared__ uint4 e_lds4[128];         // 512 ext words = 2 KB

    const int nt   = blockIdx.x;          // 0..3
    const int b    = blockIdx.y;
    const int c0   = nt * BNC_;
    const int tid  = threadIdx.x;
    const int lane = tid & 63;
    const int wv   = tid >> 6;            // 0..3 = row group of 128
    const int l31  = lane & 31;
    const int hi   = lane >> 5;

    // stage A (576 rows) + ext (512 words) for m-tile mi_ (linear, async)
    #define STAGE_AE(mi_)                                                      \
        {                                                                      \
            const char* gA = (const char*)(tsb + (size_t)b * Q_ + (mi_) * 512);\
            for (int rr = tid; rr < 576; rr += 256)                            \
                async_copy16((char*)a_lds4 + rr * 16, gA + rr * 16);           \
            if (tid < 128)                                                     \
                async_copy16((char*)e_lds4 + tid * 16,                         \
                             (const char*)(extg + (size_t)b * Q_ + (mi_) * 512)\
                             + tid * 16);                                      \
        }

    // stage B once: 64 cols x 1 KB; swizzle chunk' = chunk ^ (col&31)
    #pragma unroll
    for (int it = 0; it < 16; ++it) {
        int col  = wv * 16 + it;
        const char* g = shb + ((size_t)(c0 + col)) * 1024
                      + ((lane ^ (col & 31)) << 4);
        async_copy16((char*)b_lds4 + col * 1024, g);
    }
    STAGE_AE(0)
    __syncthreads();   // B + A0 + ext0 landed

    const f32x16 fz = {0.f,0.f,0.f,0.f,0.f,0.f,0.f,0.f,
                       0.f,0.f,0.f,0.f,0.f,0.f,0.f,0.f};
    const float inf = __builtin_inff();
    float rm0 = inf, rm1 = inf;           // running min across m-iters

    const char* bb    = (const char*)b_lds4;
    const char* ab    = (const char*)a_lds4;
    const char* eb    = (const char*)e_lds4;
    const int   abase = (wv * 128 + l31 + hi) * 16;  // ts-row byte base
    const int   bcol  = l31 * 1024;                  // B col byte base

    union UU { unsigned u[4]; s16x8 v; };
    UU be; be.u[0] = hi ? 0u : 0x3F803F80u;          // slots 0,1 = 1.0 (hi=0)
    be.u[1] = 0u; be.u[2] = 0u; be.u[3] = 0u;

    #pragma unroll 1
    for (int mi = 0; mi < 4; ++mi) {
        f32x16 acc00 = fz, acc01 = fz;    // row-group 0 (+0),   cols l31/l31+32
        f32x16 acc10 = fz, acc11 = fz;    // row-group 1 (+32)
        f32x16 acc20 = fz, acc21 = fz;    // row-group 2 (+64)
        f32x16 acc30 = fz, acc31 = fz;    // row-group 3 (+96)

        #pragma unroll
        for (int kk = 0; kk < 32; ++kk) {
            s16x8 a0 = *(const s16x8*)(ab + abase + kk * 32);
            s16x8 a1 = *(const s16x8*)(ab + abase + kk * 32 + 512);
            s16x8 a2 = *(const s16x8*)(ab + abase + kk * 32 + 1024);
            s16x8 a3 = *(const s16x8*)(ab + abase + kk * 32 + 1536);
            int ch = (((kk << 1) + hi) ^ l31) << 4;
            s16x8 b0 = *(const s16x8*)(bb + bcol + ch);
            s16x8 b1 = *(const s16x8*)(bb + bcol + ch + 32768);  // +32 cols
            __builtin_amdgcn_s_setprio(1);
            acc00 = __builtin_amdgcn_mfma_f32_32x32x16_bf16(a0, b0, acc00, 0, 0, 0);
            acc01 = __builtin_amdgcn_mfma_f32_32x32x16_bf16(a0, b1, acc01, 0, 0, 0);
            acc10 = __builtin_amdgcn_mfma_f32_32x32x16_bf16(a1, b0, acc10, 0, 0, 0);
            acc11 = __builtin_amdgcn_mfma_f32_32x32x16_bf16(a1, b1, acc11, 0, 0, 0);
            acc20 = __builtin_amdgcn_mfma_f32_32x32x16_bf16(a2, b0, acc20, 0, 0, 0);
            acc21 = __builtin_amdgcn_mfma_f32_32x32x16_bf16(a2, b1, acc21, 0, 0, 0);
            acc30 = __builtin_amdgcn_mfma_f32_32x32x16_bf16(a3, b0, acc30, 0, 0, 0);
            acc31 = __builtin_amdgcn_mfma_f32_32x32x16_bf16(a3, b1, acc31, 0, 0, 0);
            __builtin_amdgcn_s_setprio(0);
        }
        // K-extension step: fold wq (and invalid-window +inf) into acc
        {
            unsigned w0 = *(const unsigned*)(eb + (wv * 128 +  0 + l31) * 4);
            unsigned w1 = *(const unsigned*)(eb + (wv * 128 + 32 + l31) * 4);
            unsigned w2 = *(const unsigned*)(eb + (wv * 128 + 64 + l31) * 4);
            unsigned w3 = *(const unsigned*)(eb + (wv * 128 + 96 + l31) * 4);
            UU ae0, ae1, ae2, ae3;
            ae0.u[0] = hi ? 0u : w0; ae0.u[1] = 0; ae0.u[2] = 0; ae0.u[3] = 0;
            ae1.u[0] = hi ? 0u : w1; ae1.u[1] = 0; ae1.u[2] = 0; ae1.u[3] = 0;
            ae2.u[0] = hi ? 0u : w2; ae2.u[1] = 0; ae2.u[2] = 0; ae2.u[3] = 0;
            ae3.u[0] = hi ? 0u : w3; ae3.u[1] = 0; ae3.u[2] = 0; ae3.u[3] = 0;
            acc00 = __builtin_amdgcn_mfma_f32_32x32x16_bf16(ae0.v, be.v, acc00, 0, 0, 0);
            acc01 = __builtin_amdgcn_mfma_f32_32x32x16_bf16(ae0.v, be.v, acc01, 0, 0, 0);
            acc10 = __builtin_amdgcn_mfma_f32_32x32x16_bf16(ae1.v, be.v, acc10, 0, 0, 0);
            acc11 = __builtin_amdgcn_mfma_f32_32x32x16_bf16(ae1.v, be.v, acc11, 0, 0, 0);
            acc20 = __builtin_amdgcn_mfma_f32_32x32x16_bf16(ae2.v, be.v, acc20, 0, 0, 0);
            acc21 = __builtin_amdgcn_mfma_f32_32x32x16_bf16(ae2.v, be.v, acc21, 0, 0, 0);
            acc30 = __builtin_amdgcn_mfma_f32_32x32x16_bf16(ae3.v, be.v, acc30, 0, 0, 0);
            acc31 = __builtin_amdgcn_mfma_f32_32x32x16_bf16(ae3.v, be.v, acc31, 0, 0, 0);
        }
        __syncthreads();                  // all waves done reading A/ext(mi)
        if (mi < 3) STAGE_AE(mi + 1)      // issue next stage (drains at barrier)

        // register-only fold: dist*(-... ) = -2*acc already includes wq & mask
        #define FOLD(accv, rmv)                                                \
            { _Pragma("unroll") for (int r = 0; r < 16; ++r)                   \
                  rmv = fminf(rmv, -2.f * accv[r]); }
        FOLD(acc00, rm0) FOLD(acc10, rm0) FOLD(acc20, rm0) FOLD(acc30, rm0)
        FOLD(acc01, rm1) FOLD(acc11, rm1) FOLD(acc21, rm1) FOLD(acc31, rm1)
        #undef FOLD
        __syncthreads();                  // stage(mi+1) landed
    }

    // block-end epilogue: + shsq (commutes with min), scale, reduce, atomic
    const int colg = c0 + l31;
    rm0 = (rm0 + shsq[colg])      * (1.f / 512.f);
    rm1 = (rm1 + shsq[colg + 32]) * (1.f / 512.f);
    rm0 = fminf(rm0, __shfl_xor(rm0, 32, 64));
    rm1 = fminf(rm1, __shfl_xor(rm1, 32, 64));
    if (hi == 0) {
        atomicMin(&hmin[b * L_ + colg],      fenc(rm0));
        atomicMin(&hmin[b * L_ + colg + 32], fenc(rm1));
    }
}

// ---- final: gating + FC [B,L] -> [B,2] ----
__global__ __launch_bounds__(256) void k_final(const unsigned* __restrict__ hmin,
                                               const float* __restrict__ gating,
                                               const float* __restrict__ w,
                                               const float* __restrict__ bias,
                                               float* __restrict__ out) {
    const int b = blockIdx.x, t = threadIdx.x;       // 256 threads = L
    float v = fdec(hmin[b * L_ + t]);
    float g = 1.f / (1.f + __expf(-gating[t]));
    float mg = v * g;
    float p0 = mg * w[t];
    float p1 = mg * w[L_ + t];
    #pragma unroll
    for (int off = 32; off >= 1; off >>= 1) {
        p0 += __shfl_down(p0, off, 64);
        p1 += __shfl_down(p1, off, 64);
    }
    __shared__ float r0[4], r1[4];
    int wvi = t >> 6, ln = t & 63;
    if (ln == 0) { r0[wvi] = p0; r1[wvi] = p1; }
    __syncthreads();
    if (t == 0) {
        out[b * 2 + 0] = r0[0] + r0[1] + r0[2] + r0[3] + bias[0];
        out[b * 2 + 1] = r1[0] + r1[1] + r1[2] + r1[3] + bias[1];
    }
}

extern "C" void kernel_launch(void* const* d_in, const int* in_sizes, int n_in,
                              void* d_out, int out_size, void* d_ws, size_t ws_size,
                              hipStream_t stream) {
    const float* ts     = (const float*)d_in[0];
    const float* sh     = (const float*)d_in[1];
    const float* gating = (const float*)d_in[2];
    const float* fw     = (const float*)d_in[3];
    const float* fb     = (const float*)d_in[4];
    float* out = (float*)d_out;

    char* ws = (char*)d_ws;
    uint4*    tsb  = (uint4*)ws;                         // 4 MiB + 8 KB pad
    char*     shb  = ws + 4202496;                       // 256 KiB
    float*    shsq = (float*)(ws + 4464640);             // 1 KiB
    unsigned* hmin = (unsigned*)(ws + 4465664);          // 128 KiB
    unsigned* extg = (unsigned*)(ws + 4596736);          // 1 MiB

    k_prep_ts<<<128, 256, 0, stream>>>(ts, tsb, extg);
    k_misc<<<130, 256, 0, stream>>>(tsb, hmin);
    k_prep_sh<<<256, 64, 0, stream>>>(sh, (uint4*)shb, shsq);
    dim3 grid(NNT_, B_);
    k_main<<<grid, 256, 0, stream>>>(tsb, shb, extg, shsq, hmin);
    k_final<<<128, 256, 0, stream>>>(hmin, gating, fw, fb, out);
}